// Round 2
// baseline (1437.467 us; speedup 1.0000x reference)
//
#include <hip/hip_runtime.h>
#include <hip/hip_bf16.h>

#define DIM 2048
#define SEQLEN 2048
#define NHEADS 16
#define HDIM 128
#define NBATCH 2

using short8 = __attribute__((ext_vector_type(8))) short;
using f32x4 = __attribute__((ext_vector_type(4))) float;
using ushort4v = __attribute__((ext_vector_type(4))) unsigned short;

typedef __attribute__((address_space(1))) const void gvoid_t;
typedef __attribute__((address_space(3))) void lvoid_t;

__device__ __forceinline__ void gl_lds16(const void* g, void* l) {
  __builtin_amdgcn_global_load_lds((gvoid_t*)g, (lvoid_t*)l, 16, 0, 0);
}

__device__ __forceinline__ unsigned short f2bf(float f) {
  union { float f; unsigned int u; } v;
  v.f = f;
  unsigned int u = v.u;
  return (unsigned short)((u + 0x7FFFu + ((u >> 16) & 1u)) >> 16);
}

__device__ __forceinline__ f32x4 mfma16(short8 a, short8 b, f32x4 c) {
  return __builtin_amdgcn_mfma_f32_16x16x32_bf16(a, b, c, 0, 0, 0);
}

// ---------------------------------------------------------------- cast fp32->bf16
__global__ __launch_bounds__(256) void cast_all(
    const float4* __restrict__ x,
    const float4* __restrict__ wq, const float4* __restrict__ wk,
    const float4* __restrict__ wv, const float4* __restrict__ wo,
    ushort4v* __restrict__ xb,
    ushort4v* __restrict__ wqb, ushort4v* __restrict__ wkb,
    ushort4v* __restrict__ wvb, ushort4v* __restrict__ wob)
{
  const long NXV = 2097152;   // 8388608/4
  const long NWV = 1048576;   // 4194304/4
  long tid = (long)blockIdx.x * blockDim.x + threadIdx.x;
  long nth = (long)gridDim.x * blockDim.x;
  for (long i = tid; i < NXV + 4 * NWV; i += nth) {
    const float4* s; ushort4v* dst; long off;
    if (i < NXV) { s = x; dst = xb; off = i; }
    else {
      long j = i - NXV;
      int w = (int)(j >> 20);
      off = j & (NWV - 1);
      switch (w) {
        case 0:  s = wq; dst = wqb; break;
        case 1:  s = wk; dst = wkb; break;
        case 2:  s = wv; dst = wvb; break;
        default: s = wo; dst = wob; break;
      }
    }
    float4 f = s[off];
    ushort4v u;
    u.x = f2bf(f.x); u.y = f2bf(f.y); u.z = f2bf(f.z); u.w = f2bf(f.w);
    dst[off] = u;
  }
}

// ---------------------------------------------------------------- rope cos/sin tables [S][64]
__global__ __launch_bounds__(256) void rope_tables(float* __restrict__ ctab,
                                                   float* __restrict__ stab)
{
  int idx = blockIdx.x * 256 + threadIdx.x;
  if (idx >= SEQLEN * 64) return;
  int s = idx >> 6, i = idx & 63;
  float inv = powf(10000.0f, -(float)(2 * i) * (1.0f / 128.0f));
  float a = (float)s * inv;
  ctab[idx] = cosf(a);
  stab[idx] = sinf(a);
}

// ---------------------------------------------------------------- fused QKV GEMM
// C = x * [Wq;Wk;Wv]^T, M=4096, N=6144, K=2048. Segment-uniform epilogue:
// seg0 -> qb bf16 (rope, *scale); seg1 -> kout f32 + kb bf16 (rope); seg2 -> vout f32.
__global__ __launch_bounds__(256) void gemm_qkv(
    const unsigned short* __restrict__ A,
    const unsigned short* __restrict__ Wq,
    const unsigned short* __restrict__ Wk,
    const unsigned short* __restrict__ Wv,
    unsigned short* __restrict__ qbo,
    unsigned short* __restrict__ kbo,
    float* __restrict__ kout,
    float* __restrict__ vout,
    const float* __restrict__ ctab,
    const float* __restrict__ stab,
    float qscale)
{
  const int K = DIM;
  __shared__ unsigned short As[128 * 32];
  __shared__ unsigned short Bs[128 * 32];
  const int tid = threadIdx.x;
  const int wvi = tid >> 6;
  const int lane = tid & 63;
  const int q4 = lane >> 4;
  const int l15 = lane & 15;
  const int m0 = blockIdx.y * 128;
  const int n0g = blockIdx.x * 128;
  const int seg = n0g >> 11;          // 0=q,1=k,2=v (block-uniform)
  const int n0 = n0g & 2047;
  const unsigned short* B = (seg == 0) ? Wq : (seg == 1) ? Wk : Wv;
  const int wy = wvi >> 1, wx = wvi & 1;

  f32x4 acc[4][4];
  for (int i = 0; i < 4; ++i)
    for (int j = 0; j < 4; ++j)
      acc[i][j] = f32x4{0.f, 0.f, 0.f, 0.f};

  for (int k0 = 0; k0 < K; k0 += 32) {
    for (int j = 0; j < 2; ++j) {
      int sb = wvi * 128 + j * 64;
      int slot = sb + lane;
      int r = slot >> 2, c = slot & 3;
      gl_lds16(A + (size_t)(m0 + r) * K + k0 + c * 8, &As[sb * 8]);
      gl_lds16(B + (size_t)(n0 + r) * K + k0 + c * 8, &Bs[sb * 8]);
    }
    __syncthreads();
    short8 af[4], bf[4];
    for (int i = 0; i < 4; ++i)
      af[i] = *reinterpret_cast<const short8*>(&As[(wy * 64 + i * 16 + l15) * 32 + q4 * 8]);
    for (int j = 0; j < 4; ++j)
      bf[j] = *reinterpret_cast<const short8*>(&Bs[(wx * 64 + j * 16 + l15) * 32 + q4 * 8]);
    for (int i = 0; i < 4; ++i)
      for (int j = 0; j < 4; ++j)
        acc[i][j] = mfma16(af[i], bf[j], acc[i][j]);
    __syncthreads();
  }

  for (int i = 0; i < 4; ++i) {
    for (int j = 0; j < 4; ++j) {
      int colb = n0 + wx * 64 + j * 16 + l15;
      for (int r = 0; r < 4; ++r) {
        int row = m0 + wy * 64 + i * 16 + q4 * 4 + r;
        float val = acc[i][j][r];
        if (seg < 2) {  // rope for q,k
          int s = row & (SEQLEN - 1);
          int pi = (colb & (HDIM - 1)) >> 1;
          float cs = ctab[(s << 6) + pi];
          float sn = stab[(s << 6) + pi];
          float partner = __shfl_xor(val, 1);
          val = (colb & 1) ? fmaf(partner, sn, val * cs)
                           : fmaf(val, cs, -partner * sn);
        }
        size_t idx = (size_t)row * DIM + colb;
        if (seg == 0) {
          qbo[idx] = f2bf(val * qscale);
        } else if (seg == 1) {
          kout[idx] = val;
          kbo[idx] = f2bf(val);
        } else {
          vout[idx] = val;
        }
      }
    }
  }
}

// ---------------------------------------------------------------- O-projection GEMM (C=A*B^T, f32 out)
__global__ __launch_bounds__(256) void gemm_bt(
    const unsigned short* __restrict__ A,
    const unsigned short* __restrict__ B,
    float* __restrict__ Cf,
    int M, int N, int K)
{
  __shared__ unsigned short As[128 * 32];
  __shared__ unsigned short Bs[128 * 32];
  const int tid = threadIdx.x;
  const int wvi = tid >> 6;
  const int lane = tid & 63;
  const int q4 = lane >> 4;
  const int l15 = lane & 15;
  const int m0 = blockIdx.y * 128;
  const int n0 = blockIdx.x * 128;
  const int wy = wvi >> 1, wx = wvi & 1;

  f32x4 acc[4][4];
  for (int i = 0; i < 4; ++i)
    for (int j = 0; j < 4; ++j)
      acc[i][j] = f32x4{0.f, 0.f, 0.f, 0.f};

  for (int k0 = 0; k0 < K; k0 += 32) {
    for (int j = 0; j < 2; ++j) {
      int sb = wvi * 128 + j * 64;
      int slot = sb + lane;
      int r = slot >> 2, c = slot & 3;
      gl_lds16(A + (size_t)(m0 + r) * K + k0 + c * 8, &As[sb * 8]);
      gl_lds16(B + (size_t)(n0 + r) * K + k0 + c * 8, &Bs[sb * 8]);
    }
    __syncthreads();
    short8 af[4], bf[4];
    for (int i = 0; i < 4; ++i)
      af[i] = *reinterpret_cast<const short8*>(&As[(wy * 64 + i * 16 + l15) * 32 + q4 * 8]);
    for (int j = 0; j < 4; ++j)
      bf[j] = *reinterpret_cast<const short8*>(&Bs[(wx * 64 + j * 16 + l15) * 32 + q4 * 8]);
    for (int i = 0; i < 4; ++i)
      for (int j = 0; j < 4; ++j)
        acc[i][j] = mfma16(af[i], bf[j], acc[i][j]);
    __syncthreads();
  }

  for (int i = 0; i < 4; ++i)
    for (int j = 0; j < 4; ++j) {
      int colb = n0 + wx * 64 + j * 16 + l15;
      for (int r = 0; r < 4; ++r) {
        int row = m0 + wy * 64 + i * 16 + q4 * 4 + r;
        Cf[(size_t)row * N + colb] = acc[i][j][r];
      }
    }
}

// ---------------------------------------------------------------- V (B,S,D) f32 -> Vt (B*H,128,S) bf16
__global__ __launch_bounds__(256) void transpose_v(const float* __restrict__ v,
                                                   unsigned short* __restrict__ vt)
{
  __shared__ float tile[64][65];
  const int b = blockIdx.z;
  const int s0 = blockIdx.y * 64;
  const int d0 = blockIdx.x * 64;
  const int tx = threadIdx.x & 63;
  const int ty = threadIdx.x >> 6;
  for (int r = 0; r < 16; ++r) {
    int srow = r * 4 + ty;
    tile[srow][tx] = v[((size_t)(b * SEQLEN + s0 + srow)) * DIM + d0 + tx];
  }
  __syncthreads();
  for (int r = 0; r < 16; ++r) {
    int drow = r * 4 + ty;
    int d = d0 + drow;
    int bh = b * NHEADS + (d >> 7);
    int dh = d & 127;
    vt[((size_t)(bh * HDIM + dh)) * SEQLEN + s0 + tx] = f2bf(tile[tx][drow]);
  }
}

// ---------------------------------------------------------------- flash attention
// Q-tile 64 (regs, direct from global), KV-tile 64. LDS: K 16KB + Vt 16KB + P 8KB
// = 40KB -> 4 blocks/CU. Grid 1024 blocks, blockIdx.x=bh for XCD-L2 K/V locality.
// XOR-chunk swizzle c'=c^(row&7) everywhere: contiguous global_load_lds, 2-way
// (free) ds_read_b128. P written as packed bf16x2 dwords via shfl_xor pairing.
__global__ __launch_bounds__(256, 4) void flash_attn(
    const unsigned short* __restrict__ qb,
    const unsigned short* __restrict__ kb,
    const unsigned short* __restrict__ vt,
    unsigned short* __restrict__ ab)
{
  __shared__ unsigned short KP[64 * 128];   // K tile [key][dh]
  __shared__ unsigned short VTs[128 * 64];  // V tile [dh][key]
  __shared__ unsigned short Ps[64 * 64];    // P tile [q][key]
  const int tid = threadIdx.x;
  const int wvi = tid >> 6;
  const int lane = tid & 63;
  const int q4 = lane >> 4;
  const int l15 = lane & 15;
  const int bh = blockIdx.x;                // fast dim -> XCD = f(bh)
  const int q0 = blockIdx.y * 64;
  const int b = bh >> 4, h = bh & 15;

  const unsigned short* qbase = qb + (size_t)b * SEQLEN * DIM + h * HDIM;
  const unsigned short* kbase = kb + (size_t)b * SEQLEN * DIM + h * HDIM;
  const unsigned short* vbase = vt + (size_t)bh * HDIM * SEQLEN;

  // Q fragments straight from global (A-layout: m=l15 row, k-chunk=ks*4+q4)
  short8 qf[4];
  {
    const unsigned short* qrow = qbase + (size_t)(q0 + wvi * 16 + l15) * DIM;
    for (int ks = 0; ks < 4; ++ks)
      qf[ks] = *reinterpret_cast<const short8*>(qrow + (ks * 4 + q4) * 8);
  }

  float m_run[4], l_run[4];
  f32x4 o[8];
  for (int r = 0; r < 4; ++r) { m_run[r] = -3.0e38f; l_run[r] = 0.f; }
  for (int ct = 0; ct < 8; ++ct) o[ct] = f32x4{0.f, 0.f, 0.f, 0.f};

  const int par = lane & 1;

  for (int kv = 0; kv < SEQLEN / 64; ++kv) {
    const int kv0 = kv * 64;
    // stage K (64x128) and Vt (128x64), 1024 16B-slots each, 8 gl_lds16/wave
    for (int j = 0; j < 4; ++j) {
      int sb = wvi * 256 + j * 64;
      int slot = sb + lane;
      {
        int row = slot >> 4, cp = slot & 15;
        int c = cp ^ (row & 7);
        gl_lds16(kbase + (size_t)(kv0 + row) * DIM + c * 8, &KP[sb * 8]);
      }
      {
        int row = slot >> 3, cp = slot & 7;
        int c = cp ^ (row & 7);
        gl_lds16(vbase + (size_t)row * SEQLEN + kv0 + c * 8, &VTs[sb * 8]);
      }
    }
    __syncthreads();

    // QK^T: sc[ct] covers keys ct*16..+15 for this wave's 16 q rows
    f32x4 sc[4];
    for (int ct = 0; ct < 4; ++ct) sc[ct] = f32x4{0.f, 0.f, 0.f, 0.f};
    for (int ct = 0; ct < 4; ++ct) {
      int kr = ct * 16 + l15;
      for (int ks = 0; ks < 4; ++ks) {
        int c = (ks * 4 + q4) ^ (kr & 7);
        short8 kf = *reinterpret_cast<const short8*>(&KP[kr * 128 + c * 8]);
        sc[ct] = mfma16(qf[ks], kf, sc[ct]);
      }
    }

    // online softmax (row = q4*4+r, key-reduce over ct regs + 16-lane shfl)
    float al[4];
    for (int r = 0; r < 4; ++r) {
      float mx = fmaxf(fmaxf(sc[0][r], sc[1][r]), fmaxf(sc[2][r], sc[3][r]));
      for (int d = 1; d < 16; d <<= 1) mx = fmaxf(mx, __shfl_xor(mx, d));
      float mnew = fmaxf(m_run[r], mx);
      al[r] = __expf(m_run[r] - mnew);
      m_run[r] = mnew;
    }
    float rs[4] = {0.f, 0.f, 0.f, 0.f};
    for (int ct = 0; ct < 4; ++ct) {
      for (int r = 0; r < 4; ++r) {
        float e = __expf(sc[ct][r] - m_run[r]);
        sc[ct][r] = e;
        rs[r] += e;
      }
    }
    for (int r = 0; r < 4; ++r) {
      float t = rs[r];
      for (int d = 1; d < 16; d <<= 1) t += __shfl_xor(t, d);
      l_run[r] = l_run[r] * al[r] + t;
    }
    for (int ct = 0; ct < 8; ++ct)
      for (int r = 0; r < 4; ++r) o[ct][r] *= al[r];

    // P write: pack col-pairs into bf16x2 dwords; evens write rows r=0,1,
    // odds write r=2,3 -> 8 ds_write_b32 per tile, own rows only.
    for (int ct = 0; ct < 4; ++ct) {
      unsigned int pk[4];
      for (int r = 0; r < 4; ++r) {
        float own = sc[ct][r];
        float oth = __shfl_xor(own, 1);
        unsigned int a = f2bf(own), bb = f2bf(oth);
        pk[r] = par ? (bb | (a << 16)) : (a | (bb << 16));
      }
      int col0 = ct * 16 + (l15 & ~1);
      for (int rr = 0; rr < 2; ++rr) {
        int r = par * 2 + rr;
        int prow = wvi * 16 + q4 * 4 + r;
        int c = (col0 >> 3) ^ (prow & 7);
        *reinterpret_cast<unsigned int*>(&Ps[prow * 64 + c * 8 + (col0 & 7)]) = pk[r];
      }
    }
    __asm__ volatile("s_waitcnt lgkmcnt(0)" ::: "memory");

    // P frags (own 16 rows) + PV
    short8 pf[2];
    {
      int prow = wvi * 16 + l15;
      for (int ks = 0; ks < 2; ++ks) {
        int c = (ks * 4 + q4) ^ (prow & 7);
        pf[ks] = *reinterpret_cast<const short8*>(&Ps[prow * 64 + c * 8]);
      }
    }
    for (int ct = 0; ct < 8; ++ct) {
      int vr = ct * 16 + l15;
      for (int ks = 0; ks < 2; ++ks) {
        int c = (ks * 4 + q4) ^ (vr & 7);
        short8 vf = *reinterpret_cast<const short8*>(&VTs[vr * 64 + c * 8]);
        o[ct] = mfma16(pf[ks], vf, o[ct]);
      }
    }
    __syncthreads();  // K,V free for next tile's staging
  }

  for (int r = 0; r < 4; ++r) {
    float invl = 1.0f / l_run[r];
    int qrow = q0 + wvi * 16 + q4 * 4 + r;
    size_t base = ((size_t)(b * SEQLEN) + qrow) * DIM + h * HDIM;
    for (int ct = 0; ct < 8; ++ct)
      ab[base + ct * 16 + l15] = f2bf(o[ct][r] * invl);
  }
}

// ---------------------------------------------------------------- launch
extern "C" void kernel_launch(void* const* d_in, const int* in_sizes, int n_in,
                              void* d_out, int out_size, void* d_ws, size_t ws_size,
                              hipStream_t stream) {
  const float* x  = (const float*)d_in[0];
  const float* wq = (const float*)d_in[1];
  const float* wk = (const float*)d_in[2];
  const float* wv = (const float*)d_in[3];
  const float* wo = (const float*)d_in[4];

  float* outp = (float*)d_out;
  float* kout = outp + 8388608;
  float* vout = outp + 16777216;

  unsigned short* ws  = (unsigned short*)d_ws;
  unsigned short* xb  = ws;                   // 8388608
  unsigned short* wqb = xb + 8388608;         // 4194304 each
  unsigned short* wkb = wqb + 4194304;
  unsigned short* wvb = wkb + 4194304;
  unsigned short* wob = wvb + 4194304;
  unsigned short* qb  = wob + 4194304;        // 8388608 (rope'd, pre-scaled)
  unsigned short* kb  = qb + 8388608;         // 8388608 (rope'd)
  unsigned short* vtb = kb + 8388608;         // 8388608 (V^T per head)
  unsigned short* abuf = vtb + 8388608;       // 8388608 (attention out bf16)
  float* ctab = (float*)(abuf + 8388608);     // 131072 f32
  float* stab = ctab + 131072;                // 131072 f32

  cast_all<<<2048, 256, 0, stream>>>(
      (const float4*)x, (const float4*)wq, (const float4*)wk,
      (const float4*)wv, (const float4*)wo,
      (ushort4v*)xb, (ushort4v*)wqb, (ushort4v*)wkb,
      (ushort4v*)wvb, (ushort4v*)wob);
  rope_tables<<<512, 256, 0, stream>>>(ctab, stab);

  const float qscale = 0.08838834764831845f;  // 1/sqrt(128)
  gemm_qkv<<<dim3(48, 32), 256, 0, stream>>>(xb, wqb, wkb, wvb,
                                             qb, kb, kout, vout,
                                             ctab, stab, qscale);

  transpose_v<<<dim3(32, 32, 2), 256, 0, stream>>>(vout, vtb);
  flash_attn<<<dim3(32, 32), 256, 0, stream>>>(qb, kb, vtb, abuf);

  gemm_bt<<<dim3(16, 32), 256, 0, stream>>>(abuf, wob, outp, 4096, 2048, 2048);
}

// Round 3
// 1435.090 us; speedup vs baseline: 1.0017x; 1.0017x over previous
//
#include <hip/hip_runtime.h>
#include <hip/hip_bf16.h>

#define DIM 2048
#define SEQLEN 2048
#define NHEADS 16
#define HDIM 128
#define NBATCH 2

using short8 = __attribute__((ext_vector_type(8))) short;
using f32x4 = __attribute__((ext_vector_type(4))) float;
using ushort4v = __attribute__((ext_vector_type(4))) unsigned short;

typedef __attribute__((address_space(1))) const void gvoid_t;
typedef __attribute__((address_space(3))) void lvoid_t;

__device__ __forceinline__ void gl_lds16(const void* g, void* l) {
  __builtin_amdgcn_global_load_lds((gvoid_t*)g, (lvoid_t*)l, 16, 0, 0);
}

__device__ __forceinline__ unsigned short f2bf(float f) {
  union { float f; unsigned int u; } v;
  v.f = f;
  unsigned int u = v.u;
  return (unsigned short)((u + 0x7FFFu + ((u >> 16) & 1u)) >> 16);
}

__device__ __forceinline__ f32x4 mfma16(short8 a, short8 b, f32x4 c) {
  return __builtin_amdgcn_mfma_f32_16x16x32_bf16(a, b, c, 0, 0, 0);
}

// ---------------------------------------------------------------- cast fp32->bf16
__global__ __launch_bounds__(256) void cast_all(
    const float4* __restrict__ x,
    const float4* __restrict__ wq, const float4* __restrict__ wk,
    const float4* __restrict__ wv, const float4* __restrict__ wo,
    ushort4v* __restrict__ xb,
    ushort4v* __restrict__ wqb, ushort4v* __restrict__ wkb,
    ushort4v* __restrict__ wvb, ushort4v* __restrict__ wob)
{
  const long NXV = 2097152;   // 8388608/4
  const long NWV = 1048576;   // 4194304/4
  long tid = (long)blockIdx.x * blockDim.x + threadIdx.x;
  long nth = (long)gridDim.x * blockDim.x;
  for (long i = tid; i < NXV + 4 * NWV; i += nth) {
    const float4* s; ushort4v* dst; long off;
    if (i < NXV) { s = x; dst = xb; off = i; }
    else {
      long j = i - NXV;
      int w = (int)(j >> 20);
      off = j & (NWV - 1);
      switch (w) {
        case 0:  s = wq; dst = wqb; break;
        case 1:  s = wk; dst = wkb; break;
        case 2:  s = wv; dst = wvb; break;
        default: s = wo; dst = wob; break;
      }
    }
    float4 f = s[off];
    ushort4v u;
    u.x = f2bf(f.x); u.y = f2bf(f.y); u.z = f2bf(f.z); u.w = f2bf(f.w);
    dst[off] = u;
  }
}

// ---------------------------------------------------------------- rope cos/sin tables [S][64]
__global__ __launch_bounds__(256) void rope_tables(float* __restrict__ ctab,
                                                   float* __restrict__ stab)
{
  int idx = blockIdx.x * 256 + threadIdx.x;
  if (idx >= SEQLEN * 64) return;
  int s = idx >> 6, i = idx & 63;
  float inv = powf(10000.0f, -(float)(2 * i) * (1.0f / 128.0f));
  float a = (float)s * inv;
  ctab[idx] = cosf(a);
  stab[idx] = sinf(a);
}

// ---------------------------------------------------------------- fused QKV GEMM
// C = x * [Wq;Wk;Wv]^T, M=4096, N=6144, K=2048. Segment-uniform epilogue.
// __launch_bounds__(256,2): VGPR cap 256 — round-2 lesson: the default
// heuristic chose a 76-VGPR budget and SPILLED the 64-reg accumulator to
// scratch (6 GB of HBM writes, 1038 us). Cap must exceed acc+frags (~110).
__global__ __launch_bounds__(256, 2) void gemm_qkv(
    const unsigned short* __restrict__ A,
    const unsigned short* __restrict__ Wq,
    const unsigned short* __restrict__ Wk,
    const unsigned short* __restrict__ Wv,
    unsigned short* __restrict__ qbo,
    unsigned short* __restrict__ kbo,
    float* __restrict__ kout,
    float* __restrict__ vout,
    const float* __restrict__ ctab,
    const float* __restrict__ stab,
    float qscale)
{
  const int K = DIM;
  __shared__ unsigned short As[128 * 32];
  __shared__ unsigned short Bs[128 * 32];
  const int tid = threadIdx.x;
  const int wvi = tid >> 6;
  const int lane = tid & 63;
  const int q4 = lane >> 4;
  const int l15 = lane & 15;
  const int m0 = blockIdx.y * 128;
  const int n0g = blockIdx.x * 128;
  const int seg = n0g >> 11;          // 0=q,1=k,2=v (block-uniform)
  const int n0 = n0g & 2047;
  const unsigned short* B = (seg == 0) ? Wq : (seg == 1) ? Wk : Wv;
  const int wy = wvi >> 1, wx = wvi & 1;

  f32x4 acc[4][4];
  for (int i = 0; i < 4; ++i)
    for (int j = 0; j < 4; ++j)
      acc[i][j] = f32x4{0.f, 0.f, 0.f, 0.f};

  for (int k0 = 0; k0 < K; k0 += 32) {
    for (int j = 0; j < 2; ++j) {
      int sb = wvi * 128 + j * 64;
      int slot = sb + lane;
      int r = slot >> 2, c = slot & 3;
      gl_lds16(A + (size_t)(m0 + r) * K + k0 + c * 8, &As[sb * 8]);
      gl_lds16(B + (size_t)(n0 + r) * K + k0 + c * 8, &Bs[sb * 8]);
    }
    __syncthreads();
    short8 af[4], bf[4];
    for (int i = 0; i < 4; ++i)
      af[i] = *reinterpret_cast<const short8*>(&As[(wy * 64 + i * 16 + l15) * 32 + q4 * 8]);
    for (int j = 0; j < 4; ++j)
      bf[j] = *reinterpret_cast<const short8*>(&Bs[(wx * 64 + j * 16 + l15) * 32 + q4 * 8]);
    for (int i = 0; i < 4; ++i)
      for (int j = 0; j < 4; ++j)
        acc[i][j] = mfma16(af[i], bf[j], acc[i][j]);
    __syncthreads();
  }

  for (int i = 0; i < 4; ++i) {
    for (int j = 0; j < 4; ++j) {
      int colb = n0 + wx * 64 + j * 16 + l15;
      for (int r = 0; r < 4; ++r) {
        int row = m0 + wy * 64 + i * 16 + q4 * 4 + r;
        float val = acc[i][j][r];
        if (seg < 2) {  // rope for q,k
          int s = row & (SEQLEN - 1);
          int pi = (colb & (HDIM - 1)) >> 1;
          float cs = ctab[(s << 6) + pi];
          float sn = stab[(s << 6) + pi];
          float partner = __shfl_xor(val, 1);
          val = (colb & 1) ? fmaf(partner, sn, val * cs)
                           : fmaf(val, cs, -partner * sn);
        }
        size_t idx = (size_t)row * DIM + colb;
        if (seg == 0) {
          qbo[idx] = f2bf(val * qscale);
        } else if (seg == 1) {
          kout[idx] = val;
          kbo[idx] = f2bf(val);
        } else {
          vout[idx] = val;
        }
      }
    }
  }
}

// ---------------------------------------------------------------- O-projection GEMM (C=A*B^T, f32 out)
__global__ __launch_bounds__(256, 2) void gemm_bt(
    const unsigned short* __restrict__ A,
    const unsigned short* __restrict__ B,
    float* __restrict__ Cf,
    int M, int N, int K)
{
  __shared__ unsigned short As[128 * 32];
  __shared__ unsigned short Bs[128 * 32];
  const int tid = threadIdx.x;
  const int wvi = tid >> 6;
  const int lane = tid & 63;
  const int q4 = lane >> 4;
  const int l15 = lane & 15;
  const int m0 = blockIdx.y * 128;
  const int n0 = blockIdx.x * 128;
  const int wy = wvi >> 1, wx = wvi & 1;

  f32x4 acc[4][4];
  for (int i = 0; i < 4; ++i)
    for (int j = 0; j < 4; ++j)
      acc[i][j] = f32x4{0.f, 0.f, 0.f, 0.f};

  for (int k0 = 0; k0 < K; k0 += 32) {
    for (int j = 0; j < 2; ++j) {
      int sb = wvi * 128 + j * 64;
      int slot = sb + lane;
      int r = slot >> 2, c = slot & 3;
      gl_lds16(A + (size_t)(m0 + r) * K + k0 + c * 8, &As[sb * 8]);
      gl_lds16(B + (size_t)(n0 + r) * K + k0 + c * 8, &Bs[sb * 8]);
    }
    __syncthreads();
    short8 af[4], bf[4];
    for (int i = 0; i < 4; ++i)
      af[i] = *reinterpret_cast<const short8*>(&As[(wy * 64 + i * 16 + l15) * 32 + q4 * 8]);
    for (int j = 0; j < 4; ++j)
      bf[j] = *reinterpret_cast<const short8*>(&Bs[(wx * 64 + j * 16 + l15) * 32 + q4 * 8]);
    for (int i = 0; i < 4; ++i)
      for (int j = 0; j < 4; ++j)
        acc[i][j] = mfma16(af[i], bf[j], acc[i][j]);
    __syncthreads();
  }

  for (int i = 0; i < 4; ++i)
    for (int j = 0; j < 4; ++j) {
      int colb = n0 + wx * 64 + j * 16 + l15;
      for (int r = 0; r < 4; ++r) {
        int row = m0 + wy * 64 + i * 16 + q4 * 4 + r;
        Cf[(size_t)row * N + colb] = acc[i][j][r];
      }
    }
}

// ---------------------------------------------------------------- V (B,S,D) f32 -> Vt (B*H,128,S) bf16
__global__ __launch_bounds__(256) void transpose_v(const float* __restrict__ v,
                                                   unsigned short* __restrict__ vt)
{
  __shared__ float tile[64][65];
  const int b = blockIdx.z;
  const int s0 = blockIdx.y * 64;
  const int d0 = blockIdx.x * 64;
  const int tx = threadIdx.x & 63;
  const int ty = threadIdx.x >> 6;
  for (int r = 0; r < 16; ++r) {
    int srow = r * 4 + ty;
    tile[srow][tx] = v[((size_t)(b * SEQLEN + s0 + srow)) * DIM + d0 + tx];
  }
  __syncthreads();
  for (int r = 0; r < 16; ++r) {
    int drow = r * 4 + ty;
    int d = d0 + drow;
    int bh = b * NHEADS + (d >> 7);
    int dh = d & 127;
    vt[((size_t)(bh * HDIM + dh)) * SEQLEN + s0 + tx] = f2bf(tile[tx][drow]);
  }
}

// ---------------------------------------------------------------- flash attention
// Q-tile 64 (regs, direct from global), KV-tile 64. LDS: K 16KB + Vt 16KB + P 8KB
// = 40KB -> 4 blocks/CU. Grid 1024 blocks, blockIdx.x=bh for XCD-L2 K/V locality.
__global__ __launch_bounds__(256, 4) void flash_attn(
    const unsigned short* __restrict__ qb,
    const unsigned short* __restrict__ kb,
    const unsigned short* __restrict__ vt,
    unsigned short* __restrict__ ab)
{
  __shared__ unsigned short KP[64 * 128];   // K tile [key][dh]
  __shared__ unsigned short VTs[128 * 64];  // V tile [dh][key]
  __shared__ unsigned short Ps[64 * 64];    // P tile [q][key]
  const int tid = threadIdx.x;
  const int wvi = tid >> 6;
  const int lane = tid & 63;
  const int q4 = lane >> 4;
  const int l15 = lane & 15;
  const int bh = blockIdx.x;                // fast dim -> XCD = f(bh)
  const int q0 = blockIdx.y * 64;
  const int b = bh >> 4, h = bh & 15;

  const unsigned short* qbase = qb + (size_t)b * SEQLEN * DIM + h * HDIM;
  const unsigned short* kbase = kb + (size_t)b * SEQLEN * DIM + h * HDIM;
  const unsigned short* vbase = vt + (size_t)bh * HDIM * SEQLEN;

  // Q fragments straight from global (A-layout: m=l15 row, k-chunk=ks*4+q4)
  short8 qf[4];
  {
    const unsigned short* qrow = qbase + (size_t)(q0 + wvi * 16 + l15) * DIM;
    for (int ks = 0; ks < 4; ++ks)
      qf[ks] = *reinterpret_cast<const short8*>(qrow + (ks * 4 + q4) * 8);
  }

  float m_run[4], l_run[4];
  f32x4 o[8];
  for (int r = 0; r < 4; ++r) { m_run[r] = -3.0e38f; l_run[r] = 0.f; }
  for (int ct = 0; ct < 8; ++ct) o[ct] = f32x4{0.f, 0.f, 0.f, 0.f};

  const int par = lane & 1;

  for (int kv = 0; kv < SEQLEN / 64; ++kv) {
    const int kv0 = kv * 64;
    for (int j = 0; j < 4; ++j) {
      int sb = wvi * 256 + j * 64;
      int slot = sb + lane;
      {
        int row = slot >> 4, cp = slot & 15;
        int c = cp ^ (row & 7);
        gl_lds16(kbase + (size_t)(kv0 + row) * DIM + c * 8, &KP[sb * 8]);
      }
      {
        int row = slot >> 3, cp = slot & 7;
        int c = cp ^ (row & 7);
        gl_lds16(vbase + (size_t)row * SEQLEN + kv0 + c * 8, &VTs[sb * 8]);
      }
    }
    __syncthreads();

    f32x4 sc[4];
    for (int ct = 0; ct < 4; ++ct) sc[ct] = f32x4{0.f, 0.f, 0.f, 0.f};
    for (int ct = 0; ct < 4; ++ct) {
      int kr = ct * 16 + l15;
      for (int ks = 0; ks < 4; ++ks) {
        int c = (ks * 4 + q4) ^ (kr & 7);
        short8 kf = *reinterpret_cast<const short8*>(&KP[kr * 128 + c * 8]);
        sc[ct] = mfma16(qf[ks], kf, sc[ct]);
      }
    }

    float al[4];
    for (int r = 0; r < 4; ++r) {
      float mx = fmaxf(fmaxf(sc[0][r], sc[1][r]), fmaxf(sc[2][r], sc[3][r]));
      for (int d = 1; d < 16; d <<= 1) mx = fmaxf(mx, __shfl_xor(mx, d));
      float mnew = fmaxf(m_run[r], mx);
      al[r] = __expf(m_run[r] - mnew);
      m_run[r] = mnew;
    }
    float rs[4] = {0.f, 0.f, 0.f, 0.f};
    for (int ct = 0; ct < 4; ++ct) {
      for (int r = 0; r < 4; ++r) {
        float e = __expf(sc[ct][r] - m_run[r]);
        sc[ct][r] = e;
        rs[r] += e;
      }
    }
    for (int r = 0; r < 4; ++r) {
      float t = rs[r];
      for (int d = 1; d < 16; d <<= 1) t += __shfl_xor(t, d);
      l_run[r] = l_run[r] * al[r] + t;
    }
    for (int ct = 0; ct < 8; ++ct)
      for (int r = 0; r < 4; ++r) o[ct][r] *= al[r];

    for (int ct = 0; ct < 4; ++ct) {
      unsigned int pk[4];
      for (int r = 0; r < 4; ++r) {
        float own = sc[ct][r];
        float oth = __shfl_xor(own, 1);
        unsigned int a = f2bf(own), bb = f2bf(oth);
        pk[r] = par ? (bb | (a << 16)) : (a | (bb << 16));
      }
      int col0 = ct * 16 + (l15 & ~1);
      for (int rr = 0; rr < 2; ++rr) {
        int r = par * 2 + rr;
        int prow = wvi * 16 + q4 * 4 + r;
        int c = (col0 >> 3) ^ (prow & 7);
        *reinterpret_cast<unsigned int*>(&Ps[prow * 64 + c * 8 + (col0 & 7)]) = pk[r];
      }
    }
    __asm__ volatile("s_waitcnt lgkmcnt(0)" ::: "memory");

    short8 pf[2];
    {
      int prow = wvi * 16 + l15;
      for (int ks = 0; ks < 2; ++ks) {
        int c = (ks * 4 + q4) ^ (prow & 7);
        pf[ks] = *reinterpret_cast<const short8*>(&Ps[prow * 64 + c * 8]);
      }
    }
    for (int ct = 0; ct < 8; ++ct) {
      int vr = ct * 16 + l15;
      for (int ks = 0; ks < 2; ++ks) {
        int c = (ks * 4 + q4) ^ (vr & 7);
        short8 vf = *reinterpret_cast<const short8*>(&VTs[vr * 64 + c * 8]);
        o[ct] = mfma16(pf[ks], vf, o[ct]);
      }
    }
    __syncthreads();
  }

  for (int r = 0; r < 4; ++r) {
    float invl = 1.0f / l_run[r];
    int qrow = q0 + wvi * 16 + q4 * 4 + r;
    size_t base = ((size_t)(b * SEQLEN) + qrow) * DIM + h * HDIM;
    for (int ct = 0; ct < 8; ++ct)
      ab[base + ct * 16 + l15] = f2bf(o[ct][r] * invl);
  }
}

// ---------------------------------------------------------------- launch
extern "C" void kernel_launch(void* const* d_in, const int* in_sizes, int n_in,
                              void* d_out, int out_size, void* d_ws, size_t ws_size,
                              hipStream_t stream) {
  const float* x  = (const float*)d_in[0];
  const float* wq = (const float*)d_in[1];
  const float* wk = (const float*)d_in[2];
  const float* wv = (const float*)d_in[3];
  const float* wo = (const float*)d_in[4];

  float* outp = (float*)d_out;
  float* kout = outp + 8388608;
  float* vout = outp + 16777216;

  unsigned short* ws  = (unsigned short*)d_ws;
  unsigned short* xb  = ws;                   // 8388608
  unsigned short* wqb = xb + 8388608;         // 4194304 each
  unsigned short* wkb = wqb + 4194304;
  unsigned short* wvb = wkb + 4194304;
  unsigned short* wob = wvb + 4194304;
  unsigned short* qb  = wob + 4194304;        // 8388608 (rope'd, pre-scaled)
  unsigned short* kb  = qb + 8388608;         // 8388608 (rope'd)
  unsigned short* vtb = kb + 8388608;         // 8388608 (V^T per head)
  unsigned short* abuf = vtb + 8388608;       // 8388608 (attention out bf16)
  float* ctab = (float*)(abuf + 8388608);     // 131072 f32
  float* stab = ctab + 131072;                // 131072 f32

  cast_all<<<2048, 256, 0, stream>>>(
      (const float4*)x, (const float4*)wq, (const float4*)wk,
      (const float4*)wv, (const float4*)wo,
      (ushort4v*)xb, (ushort4v*)wqb, (ushort4v*)wkb,
      (ushort4v*)wvb, (ushort4v*)wob);
  rope_tables<<<512, 256, 0, stream>>>(ctab, stab);

  const float qscale = 0.08838834764831845f;  // 1/sqrt(128)
  gemm_qkv<<<dim3(48, 32), 256, 0, stream>>>(xb, wqb, wkb, wvb,
                                             qb, kb, kout, vout,
                                             ctab, stab, qscale);

  transpose_v<<<dim3(32, 32, 2), 256, 0, stream>>>(vout, vtb);
  flash_attn<<<dim3(32, 32), 256, 0, stream>>>(qb, kb, vtb, abuf);

  gemm_bt<<<dim3(16, 32), 256, 0, stream>>>(abuf, wob, outp, 4096, 2048, 2048);
}

// Round 5
// 630.407 us; speedup vs baseline: 2.2802x; 2.2764x over previous
//
#include <hip/hip_runtime.h>
#include <hip/hip_bf16.h>

#define DIM 2048
#define SEQLEN 2048
#define NHEADS 16
#define HDIM 128
#define NBATCH 2

using short8 = __attribute__((ext_vector_type(8))) short;
using f32x4 = __attribute__((ext_vector_type(4))) float;
using ushort4v = __attribute__((ext_vector_type(4))) unsigned short;

typedef __attribute__((address_space(1))) const void gvoid_t;
typedef __attribute__((address_space(3))) void lvoid_t;

__device__ __forceinline__ void gl_lds16(const void* g, void* l) {
  __builtin_amdgcn_global_load_lds((gvoid_t*)g, (lvoid_t*)l, 16, 0, 0);
}

__device__ __forceinline__ unsigned short f2bf(float f) {
  union { float f; unsigned int u; } v;
  v.f = f;
  unsigned int u = v.u;
  return (unsigned short)((u + 0x7FFFu + ((u >> 16) & 1u)) >> 16);
}

__device__ __forceinline__ f32x4 mfma16(short8 a, short8 b, f32x4 c) {
  return __builtin_amdgcn_mfma_f32_16x16x32_bf16(a, b, c, 0, 0, 0);
}

// ---------------------------------------------------------------- cast fp32->bf16
__global__ __launch_bounds__(256) void cast_all(
    const float4* __restrict__ x,
    const float4* __restrict__ wq, const float4* __restrict__ wk,
    const float4* __restrict__ wv, const float4* __restrict__ wo,
    ushort4v* __restrict__ xb,
    ushort4v* __restrict__ wqb, ushort4v* __restrict__ wkb,
    ushort4v* __restrict__ wvb, ushort4v* __restrict__ wob)
{
  const long NXV = 2097152;   // 8388608/4
  const long NWV = 1048576;   // 4194304/4
  long tid = (long)blockIdx.x * blockDim.x + threadIdx.x;
  long nth = (long)gridDim.x * blockDim.x;
  for (long i = tid; i < NXV + 4 * NWV; i += nth) {
    const float4* s; ushort4v* dst; long off;
    if (i < NXV) { s = x; dst = xb; off = i; }
    else {
      long j = i - NXV;
      int w = (int)(j >> 20);
      off = j & (NWV - 1);
      switch (w) {
        case 0:  s = wq; dst = wqb; break;
        case 1:  s = wk; dst = wkb; break;
        case 2:  s = wv; dst = wvb; break;
        default: s = wo; dst = wob; break;
      }
    }
    float4 f = s[off];
    ushort4v u;
    u.x = f2bf(f.x); u.y = f2bf(f.y); u.z = f2bf(f.z); u.w = f2bf(f.w);
    dst[off] = u;
  }
}

// ---------------------------------------------------------------- rope cos/sin tables [S][64]
__global__ __launch_bounds__(256) void rope_tables(float* __restrict__ ctab,
                                                   float* __restrict__ stab)
{
  int idx = blockIdx.x * 256 + threadIdx.x;
  if (idx >= SEQLEN * 64) return;
  int s = idx >> 6, i = idx & 63;
  float inv = powf(10000.0f, -(float)(2 * i) * (1.0f / 128.0f));
  float a = (float)s * inv;
  ctab[idx] = cosf(a);
  stab[idx] = sinf(a);
}

// ---------------------------------------------------------------- GEMM C = A*B^T (A:MxK, B:NxK, bf16)
// m97 structure. COMPILE-TIME epilogue flags only — round-2/3 lesson: a fused
// runtime-branching multi-target epilogue flips the register-allocator
// heuristic to an 8-waves/EU target (VGPR=60) and the accumulator lives in
// scratch for the whole K-loop: 6 GB of HBM writes, 1035 us. Keep the
// epilogue shape compile-time-simple; plain __launch_bounds__(256).
template<bool ROPE, bool WF32, bool WBF16>
__global__ __launch_bounds__(256) void gemm_bt(
    const unsigned short* __restrict__ A,
    const unsigned short* __restrict__ B,
    float* __restrict__ Cf,
    unsigned short* __restrict__ Cb,
    int M, int N, int K,
    const float* __restrict__ ctab,
    const float* __restrict__ stab,
    float premul)
{
  __shared__ unsigned short As[128 * 32];
  __shared__ unsigned short Bs[128 * 32];
  const int tid = threadIdx.x;
  const int wv = tid >> 6;
  const int lane = tid & 63;
  const int q4 = lane >> 4;
  const int l15 = lane & 15;
  const int m0 = blockIdx.y * 128;
  const int n0 = blockIdx.x * 128;
  const int wy = wv >> 1, wx = wv & 1;   // 2x2 waves, 64x64 each

  f32x4 acc[4][4];
  for (int i = 0; i < 4; ++i)
    for (int j = 0; j < 4; ++j)
      acc[i][j] = f32x4{0.f, 0.f, 0.f, 0.f};

  for (int k0 = 0; k0 < K; k0 += 32) {
    for (int j = 0; j < 2; ++j) {
      int sb = wv * 128 + j * 64;
      int slot = sb + lane;
      int r = slot >> 2, c = slot & 3;
      gl_lds16(A + (size_t)(m0 + r) * K + k0 + c * 8, &As[sb * 8]);
      gl_lds16(B + (size_t)(n0 + r) * K + k0 + c * 8, &Bs[sb * 8]);
    }
    __syncthreads();
    short8 af[4], bf[4];
    for (int i = 0; i < 4; ++i)
      af[i] = *reinterpret_cast<const short8*>(&As[(wy * 64 + i * 16 + l15) * 32 + q4 * 8]);
    for (int j = 0; j < 4; ++j)
      bf[j] = *reinterpret_cast<const short8*>(&Bs[(wx * 64 + j * 16 + l15) * 32 + q4 * 8]);
    for (int i = 0; i < 4; ++i)
      for (int j = 0; j < 4; ++j)
        acc[i][j] = mfma16(af[i], bf[j], acc[i][j]);
    __syncthreads();
  }

  // epilogue: C/D layout col=lane&15, row=(lane>>4)*4+reg (m89-verified)
  for (int i = 0; i < 4; ++i) {
    for (int j = 0; j < 4; ++j) {
      int colb = n0 + wx * 64 + j * 16 + l15;
      for (int r = 0; r < 4; ++r) {
        int row = m0 + wy * 64 + i * 16 + q4 * 4 + r;
        float val = acc[i][j][r];
        if (ROPE) {
          int s = row & (SEQLEN - 1);
          int pi = (colb & (HDIM - 1)) >> 1;
          float cs = ctab[(s << 6) + pi];
          float sn = stab[(s << 6) + pi];
          float partner = __shfl_xor(val, 1);  // adjacent head-dim column = adjacent lane
          val = (colb & 1) ? fmaf(partner, sn, val * cs)
                           : fmaf(val, cs, -partner * sn);
        }
        if (WF32) Cf[(size_t)row * N + colb] = val;
        if (WBF16) Cb[(size_t)row * N + colb] = f2bf(val * premul);
      }
    }
  }
}

// ---------------------------------------------------------------- V (B,S,D) f32 -> Vt (B*H,128,S) bf16
__global__ __launch_bounds__(256) void transpose_v(const float* __restrict__ v,
                                                   unsigned short* __restrict__ vt)
{
  __shared__ float tile[64][65];
  const int b = blockIdx.z;
  const int s0 = blockIdx.y * 64;
  const int d0 = blockIdx.x * 64;
  const int tx = threadIdx.x & 63;
  const int ty = threadIdx.x >> 6;
  for (int r = 0; r < 16; ++r) {
    int srow = r * 4 + ty;
    tile[srow][tx] = v[((size_t)(b * SEQLEN + s0 + srow)) * DIM + d0 + tx];
  }
  __syncthreads();
  for (int r = 0; r < 16; ++r) {
    int drow = r * 4 + ty;
    int d = d0 + drow;
    int bh = b * NHEADS + (d >> 7);
    int dh = d & 127;
    vt[((size_t)(bh * HDIM + dh)) * SEQLEN + s0 + tx] = f2bf(tile[tx][drow]);
  }
}

// ---------------------------------------------------------------- flash attention
// Q-tile 64 (regs, direct from global), KV-tile 64. LDS: K 16KB + Vt 16KB + P 8KB
// = 40KB -> 4 blocks/CU. Grid 1024 blocks, blockIdx.x=bh for XCD-L2 K/V locality.
__global__ __launch_bounds__(256, 4) void flash_attn(
    const unsigned short* __restrict__ qb,
    const unsigned short* __restrict__ kb,
    const unsigned short* __restrict__ vt,
    unsigned short* __restrict__ ab)
{
  __shared__ unsigned short KP[64 * 128];   // K tile [key][dh]
  __shared__ unsigned short VTs[128 * 64];  // V tile [dh][key]
  __shared__ unsigned short Ps[64 * 64];    // P tile [q][key]
  const int tid = threadIdx.x;
  const int wvi = tid >> 6;
  const int lane = tid & 63;
  const int q4 = lane >> 4;
  const int l15 = lane & 15;
  const int bh = blockIdx.x;                // fast dim -> XCD = f(bh)
  const int q0 = blockIdx.y * 64;
  const int b = bh >> 4, h = bh & 15;

  const unsigned short* qbase = qb + (size_t)b * SEQLEN * DIM + h * HDIM;
  const unsigned short* kbase = kb + (size_t)b * SEQLEN * DIM + h * HDIM;
  const unsigned short* vbase = vt + (size_t)bh * HDIM * SEQLEN;

  // Q fragments straight from global (A-layout: m=l15 row, k-chunk=ks*4+q4)
  short8 qf[4];
  {
    const unsigned short* qrow = qbase + (size_t)(q0 + wvi * 16 + l15) * DIM;
    for (int ks = 0; ks < 4; ++ks)
      qf[ks] = *reinterpret_cast<const short8*>(qrow + (ks * 4 + q4) * 8);
  }

  float m_run[4], l_run[4];
  f32x4 o[8];
  for (int r = 0; r < 4; ++r) { m_run[r] = -3.0e38f; l_run[r] = 0.f; }
  for (int ct = 0; ct < 8; ++ct) o[ct] = f32x4{0.f, 0.f, 0.f, 0.f};

  const int par = lane & 1;

  for (int kv = 0; kv < SEQLEN / 64; ++kv) {
    const int kv0 = kv * 64;
    for (int j = 0; j < 4; ++j) {
      int sb = wvi * 256 + j * 64;
      int slot = sb + lane;
      {
        int row = slot >> 4, cp = slot & 15;
        int c = cp ^ (row & 7);
        gl_lds16(kbase + (size_t)(kv0 + row) * DIM + c * 8, &KP[sb * 8]);
      }
      {
        int row = slot >> 3, cp = slot & 7;
        int c = cp ^ (row & 7);
        gl_lds16(vbase + (size_t)row * SEQLEN + kv0 + c * 8, &VTs[sb * 8]);
      }
    }
    __syncthreads();

    f32x4 sc[4];
    for (int ct = 0; ct < 4; ++ct) sc[ct] = f32x4{0.f, 0.f, 0.f, 0.f};
    for (int ct = 0; ct < 4; ++ct) {
      int kr = ct * 16 + l15;
      for (int ks = 0; ks < 4; ++ks) {
        int c = (ks * 4 + q4) ^ (kr & 7);
        short8 kf = *reinterpret_cast<const short8*>(&KP[kr * 128 + c * 8]);
        sc[ct] = mfma16(qf[ks], kf, sc[ct]);
      }
    }

    float al[4];
    for (int r = 0; r < 4; ++r) {
      float mx = fmaxf(fmaxf(sc[0][r], sc[1][r]), fmaxf(sc[2][r], sc[3][r]));
      for (int d = 1; d < 16; d <<= 1) mx = fmaxf(mx, __shfl_xor(mx, d));
      float mnew = fmaxf(m_run[r], mx);
      al[r] = __expf(m_run[r] - mnew);
      m_run[r] = mnew;
    }
    float rs[4] = {0.f, 0.f, 0.f, 0.f};
    for (int ct = 0; ct < 4; ++ct) {
      for (int r = 0; r < 4; ++r) {
        float e = __expf(sc[ct][r] - m_run[r]);
        sc[ct][r] = e;
        rs[r] += e;
      }
    }
    for (int r = 0; r < 4; ++r) {
      float t = rs[r];
      for (int d = 1; d < 16; d <<= 1) t += __shfl_xor(t, d);
      l_run[r] = l_run[r] * al[r] + t;
    }
    for (int ct = 0; ct < 8; ++ct)
      for (int r = 0; r < 4; ++r) o[ct][r] *= al[r];

    for (int ct = 0; ct < 4; ++ct) {
      unsigned int pk[4];
      for (int r = 0; r < 4; ++r) {
        float own = sc[ct][r];
        float oth = __shfl_xor(own, 1);
        unsigned int a = f2bf(own), bb = f2bf(oth);
        pk[r] = par ? (bb | (a << 16)) : (a | (bb << 16));
      }
      int col0 = ct * 16 + (l15 & ~1);
      for (int rr = 0; rr < 2; ++rr) {
        int r = par * 2 + rr;
        int prow = wvi * 16 + q4 * 4 + r;
        int c = (col0 >> 3) ^ (prow & 7);
        *reinterpret_cast<unsigned int*>(&Ps[prow * 64 + c * 8 + (col0 & 7)]) = pk[r];
      }
    }
    __asm__ volatile("s_waitcnt lgkmcnt(0)" ::: "memory");

    short8 pf[2];
    {
      int prow = wvi * 16 + l15;
      for (int ks = 0; ks < 2; ++ks) {
        int c = (ks * 4 + q4) ^ (prow & 7);
        pf[ks] = *reinterpret_cast<const short8*>(&Ps[prow * 64 + c * 8]);
      }
    }
    for (int ct = 0; ct < 8; ++ct) {
      int vr = ct * 16 + l15;
      for (int ks = 0; ks < 2; ++ks) {
        int c = (ks * 4 + q4) ^ (vr & 7);
        short8 vf = *reinterpret_cast<const short8*>(&VTs[vr * 64 + c * 8]);
        o[ct] = mfma16(pf[ks], vf, o[ct]);
      }
    }
    __syncthreads();
  }

  for (int r = 0; r < 4; ++r) {
    float invl = 1.0f / l_run[r];
    int qrow = q0 + wvi * 16 + q4 * 4 + r;
    size_t base = ((size_t)(b * SEQLEN) + qrow) * DIM + h * HDIM;
    for (int ct = 0; ct < 8; ++ct)
      ab[base + ct * 16 + l15] = f2bf(o[ct][r] * invl);
  }
}

// ---------------------------------------------------------------- launch
extern "C" void kernel_launch(void* const* d_in, const int* in_sizes, int n_in,
                              void* d_out, int out_size, void* d_ws, size_t ws_size,
                              hipStream_t stream) {
  const float* x  = (const float*)d_in[0];
  const float* wq = (const float*)d_in[1];
  const float* wk = (const float*)d_in[2];
  const float* wv = (const float*)d_in[3];
  const float* wo = (const float*)d_in[4];

  float* outp = (float*)d_out;
  float* kout = outp + 8388608;
  float* vout = outp + 16777216;

  unsigned short* ws  = (unsigned short*)d_ws;
  unsigned short* xb  = ws;                   // 8388608
  unsigned short* wqb = xb + 8388608;         // 4194304 each
  unsigned short* wkb = wqb + 4194304;
  unsigned short* wvb = wkb + 4194304;
  unsigned short* wob = wvb + 4194304;
  unsigned short* qb  = wob + 4194304;        // 8388608 (rope'd, pre-scaled)
  unsigned short* kb  = qb + 8388608;         // 8388608 (rope'd)
  unsigned short* vtb = kb + 8388608;         // 8388608 (V^T per head)
  unsigned short* abuf = vtb + 8388608;       // 8388608 (attention out bf16)
  float* ctab = (float*)(abuf + 8388608);     // 131072 f32
  float* stab = ctab + 131072;                // 131072 f32

  cast_all<<<2048, 256, 0, stream>>>(
      (const float4*)x, (const float4*)wq, (const float4*)wk,
      (const float4*)wv, (const float4*)wo,
      (ushort4v*)xb, (ushort4v*)wqb, (ushort4v*)wkb,
      (ushort4v*)wvb, (ushort4v*)wob);
  rope_tables<<<512, 256, 0, stream>>>(ctab, stab);

  dim3 gg(16, 32);  // N/128, M/128
  const float qscale = 0.08838834764831845f;  // 1/sqrt(128)
  gemm_bt<true,  false, true ><<<gg, 256, 0, stream>>>(xb, wqb, nullptr, qb, 4096, 2048, 2048, ctab, stab, qscale);
  gemm_bt<true,  true,  true ><<<gg, 256, 0, stream>>>(xb, wkb, kout,    kb, 4096, 2048, 2048, ctab, stab, 1.0f);
  gemm_bt<false, true,  false><<<gg, 256, 0, stream>>>(xb, wvb, vout, nullptr, 4096, 2048, 2048, ctab, stab, 1.0f);

  transpose_v<<<dim3(32, 32, 2), 256, 0, stream>>>(vout, vtb);
  flash_attn<<<dim3(32, 32), 256, 0, stream>>>(qb, kb, vtb, abuf);

  gemm_bt<false, true,  false><<<gg, 256, 0, stream>>>(abuf, wob, outp, nullptr, 4096, 2048, 2048, ctab, stab, 1.0f);
}